// Round 2
// baseline (416.141 us; speedup 1.0000x reference)
//
#include <hip/hip_runtime.h>
#include <stdint.h>

// GCN: out[u] = (sum_{(u,v) in E} x[v]) @ W + bias
// Edges sorted by u (np.unique guarantees), so each wave scans a contiguous
// edge segment for its 16 rows — no atomics. Single fused kernel.
// NOTE: harness materializes integer inputs as int32 (const int*), NOT int64.

typedef __attribute__((ext_vector_type(8))) short bf16x8;   // 8 bf16 = 4 VGPRs
typedef __attribute__((ext_vector_type(4))) float f32x4;    // MFMA C/D

#define WSTRIDE 136   // padded k-stride (bf16 elems): 272 B rows -> 2-way (free) LDS banks

__device__ __forceinline__ unsigned short f2bf(float f) {
    union { float f; uint32_t u; } c; c.f = f;
    uint32_t u = c.u;
    // round-to-nearest-even
    uint32_t r = (u + 0x7FFFu + ((u >> 16) & 1u)) >> 16;
    return (unsigned short)r;
}

__global__ __launch_bounds__(256)
void gcn_fused(const float* __restrict__ x,
               const int* __restrict__ eu,   // edge_index row 0 (dst), sorted, int32
               const int* __restrict__ ev,   // edge_index row 1 (src), int32
               const float* __restrict__ W,  // [128][128] f32, k-major
               const float* __restrict__ bias,
               float* __restrict__ out,      // [N][128] f32
               int N, int E)
{
    __shared__ __align__(16) unsigned short Wt[128 * WSTRIDE];   // W^T as bf16: Wt[n][k]
    __shared__ __align__(16) unsigned short At[4][16 * WSTRIDE]; // per-wave agg tile [m][k]

    const int t    = threadIdx.x;
    const int wid  = t >> 6;
    const int lane = t & 63;
    const int quad = lane >> 4;
    const int l15  = lane & 15;

    // ---- Phase 0: W (k-major f32) -> Wt (n-major bf16), cooperative ----
    {
        const float4* W4 = (const float4*)W;
        #pragma unroll
        for (int i = 0; i < 16; ++i) {
            int flat = i * 1024 + t * 4;        // element index into W
            int k = flat >> 7;
            int n = flat & 127;
            float4 w = W4[flat >> 2];           // coalesced
            Wt[(n + 0) * WSTRIDE + k] = f2bf(w.x);
            Wt[(n + 1) * WSTRIDE + k] = f2bf(w.y);
            Wt[(n + 2) * WSTRIDE + k] = f2bf(w.z);
            Wt[(n + 3) * WSTRIDE + k] = f2bf(w.w);
        }
    }
    __syncthreads();   // Wt visible to all waves

    // ---- Phase 1: aggregate 16 rows per wave (sorted-edge scan) ----
    const int rowbase = blockIdx.x * 64 + wid * 16;

    // lower_bound(eu, rowbase) — wave-uniform binary search (broadcast loads)
    int lo = 0, hi = E;
    while (lo < hi) {
        int mid = (lo + hi) >> 1;
        if (eu[mid] < rowbase) lo = mid + 1; else hi = mid;
    }
    int e = lo;

    unsigned short* Am = &At[wid][0];
    for (int m = 0; m < 16; ++m) {
        const int row = rowbase + m;
        float ax = 0.f, ay = 0.f;
        while (e < E && eu[e] == row) {
            long long v = (long long)ev[e];
            float2 tv = ((const float2*)(x + (v << 7)))[lane];  // coalesced 512B/edge
            ax += tv.x; ay += tv.y;
            ++e;
        }
        // lane holds features 2*lane, 2*lane+1 of row m
        Am[m * WSTRIDE + 2 * lane + 0] = f2bf(ax);
        Am[m * WSTRIDE + 2 * lane + 1] = f2bf(ay);
    }
    __syncthreads();   // cheap (once/block): guarantee At write->read ordering

    // ---- Phase 2: [16 x 128] = A @ W via mfma_f32_16x16x32_bf16 ----
    f32x4 acc[8];
    #pragma unroll
    for (int nt = 0; nt < 8; ++nt) { acc[nt].x = 0.f; acc[nt].y = 0.f; acc[nt].z = 0.f; acc[nt].w = 0.f; }

    #pragma unroll
    for (int ks = 0; ks < 4; ++ks) {
        const int kofs = ks * 32 + quad * 8;
        bf16x8 a = *(const bf16x8*)(Am + l15 * WSTRIDE + kofs);   // A[m=l15][k..k+7]
        #pragma unroll
        for (int nt = 0; nt < 8; ++nt) {
            bf16x8 b = *(const bf16x8*)(Wt + (nt * 16 + l15) * WSTRIDE + kofs); // B^T[n=l15][k..k+7]
            acc[nt] = __builtin_amdgcn_mfma_f32_16x16x32_bf16(a, b, acc[nt], 0, 0, 0);
        }
    }

    // ---- Phase 3: epilogue. C/D: col = lane&15, row = quad*4 + reg ----
    #pragma unroll
    for (int nt = 0; nt < 8; ++nt) {
        const int col = nt * 16 + l15;
        const float bcol = bias[col];
        #pragma unroll
        for (int r = 0; r < 4; ++r) {
            const int row = rowbase + quad * 4 + r;
            if (row < N) out[(long long)row * 128 + col] = acc[nt][r] + bcol;
        }
    }
}

extern "C" void kernel_launch(void* const* d_in, const int* in_sizes, int n_in,
                              void* d_out, int out_size, void* d_ws, size_t ws_size,
                              hipStream_t stream) {
    const float* x    = (const float*)d_in[0];
    const int*   ei   = (const int*)d_in[1];     // int32 on device (harness convention)
    const float* W    = (const float*)d_in[2];
    const float* bias = (const float*)d_in[3];
    float*       out  = (float*)d_out;

    const int N = in_sizes[0] / 128;
    const int E = in_sizes[1] / 2;

    const int grid = (N + 63) / 64;   // 64 rows per block (16 per wave)
    gcn_fused<<<grid, 256, 0, stream>>>(x, ei, ei + E, W, bias, out, N, E);
}

// Round 3
// 179.807 us; speedup vs baseline: 2.3144x; 2.3144x over previous
//
#include <hip/hip_runtime.h>
#include <stdint.h>

// GCN: out[u] = (sum_{(u,v) in E} x[v]) @ W + bias
// Edges sorted by u (np.unique). Per wave: 16 rows. Row boundaries found by
// 17 parallel binary searches (one per lane 0..16), then counted inner loops
// with unroll-4 independent gathers (breaks the serial eu-compare chain that
// made R2 latency-bound at 360us: VALUBusy 4.3%, HBM 5.6%).

typedef __attribute__((ext_vector_type(8))) short bf16x8;   // 8 bf16 = 4 VGPRs
typedef __attribute__((ext_vector_type(4))) float f32x4;    // MFMA C/D

#define WSTRIDE 136   // padded k-stride (bf16 elems), multiple of 8 for 16B reads

__device__ __forceinline__ unsigned short f2bf(float f) {
    union { float f; uint32_t u; } c; c.f = f;
    uint32_t u = c.u;
    uint32_t r = (u + 0x7FFFu + ((u >> 16) & 1u)) >> 16;  // RNE
    return (unsigned short)r;
}

__global__ __launch_bounds__(256)
void gcn_fused(const float* __restrict__ x,
               const int* __restrict__ eu,   // dst row ids, sorted, int32
               const int* __restrict__ ev,   // src row ids, int32
               const float* __restrict__ W,  // [128][128] f32, k-major
               const float* __restrict__ bias,
               float* __restrict__ out,      // [N][128] f32
               int N, int E)
{
    __shared__ __align__(16) unsigned short Wt[128 * WSTRIDE];   // W^T bf16: Wt[n][k]
    __shared__ __align__(16) unsigned short At[4][16 * WSTRIDE]; // per-wave agg [m][k]

    const int t    = threadIdx.x;
    const int wid  = t >> 6;
    const int lane = t & 63;
    const int quad = lane >> 4;
    const int l15  = lane & 15;

    // ---- Phase 0: W (k-major f32) -> Wt (n-major bf16), cooperative ----
    {
        const float4* W4 = (const float4*)W;
        #pragma unroll
        for (int i = 0; i < 16; ++i) {
            int flat = i * 1024 + t * 4;
            int k = flat >> 7;
            int n = flat & 127;
            float4 w = W4[flat >> 2];
            Wt[(n + 0) * WSTRIDE + k] = f2bf(w.x);
            Wt[(n + 1) * WSTRIDE + k] = f2bf(w.y);
            Wt[(n + 2) * WSTRIDE + k] = f2bf(w.z);
            Wt[(n + 3) * WSTRIDE + k] = f2bf(w.w);
        }
    }
    __syncthreads();

    // ---- Phase 1a: 17 parallel binary searches for row boundaries ----
    const int rowbase = blockIdx.x * 64 + wid * 16;
    {
        // lane i (i<=16) finds lower_bound(eu, rowbase+i); others clamp to 16.
        int tgt = rowbase + (lane < 16 ? lane : 16);
        int lo = 0, hi = E;
        while (lo < hi) {
            int mid = (lo + hi) >> 1;
            if (eu[mid] < tgt) lo = mid + 1; else hi = mid;
        }
        // stash in a register; broadcast below via shfl
        // (reuse variable name via scope)
        // Phase 1b: per-row counted gather loops
        unsigned short* Am = &At[wid][0];
        const float2* x2 = (const float2*)x;
        for (int m = 0; m < 16; ++m) {
            const int s   = __shfl(lo, m);
            const int cnt = __shfl(lo, m + 1) - s;
            const int* evs = ev + s;
            float a0 = 0.f, a1 = 0.f, b0 = 0.f, b1 = 0.f;
            float c0 = 0.f, c1 = 0.f, d0 = 0.f, d1 = 0.f;
            int j = 0;
            for (; j + 4 <= cnt; j += 4) {
                int v0 = evs[j], v1 = evs[j + 1], v2 = evs[j + 2], v3 = evs[j + 3];
                float2 t0 = x2[((long long)v0 << 6) + lane];
                float2 t1 = x2[((long long)v1 << 6) + lane];
                float2 t2 = x2[((long long)v2 << 6) + lane];
                float2 t3 = x2[((long long)v3 << 6) + lane];
                a0 += t0.x; a1 += t0.y;
                b0 += t1.x; b1 += t1.y;
                c0 += t2.x; c1 += t2.y;
                d0 += t3.x; d1 += t3.y;
            }
            for (; j < cnt; ++j) {
                int v = evs[j];
                float2 tv = x2[((long long)v << 6) + lane];
                a0 += tv.x; a1 += tv.y;
            }
            float ax = (a0 + b0) + (c0 + d0);
            float ay = (a1 + b1) + (c1 + d1);
            Am[m * WSTRIDE + 2 * lane + 0] = f2bf(ax);
            Am[m * WSTRIDE + 2 * lane + 1] = f2bf(ay);
        }
    }
    __syncthreads();   // once per block; guarantees At ordering for MFMA reads

    // ---- Phase 2: [16 x 128] = A @ W via mfma_f32_16x16x32_bf16 ----
    const unsigned short* Am = &At[wid][0];
    f32x4 acc[8];
    #pragma unroll
    for (int nt = 0; nt < 8; ++nt) { acc[nt].x = 0.f; acc[nt].y = 0.f; acc[nt].z = 0.f; acc[nt].w = 0.f; }

    #pragma unroll
    for (int ks = 0; ks < 4; ++ks) {
        const int kofs = ks * 32 + quad * 8;
        bf16x8 a = *(const bf16x8*)(Am + l15 * WSTRIDE + kofs);   // A[m=l15][k..k+7]
        #pragma unroll
        for (int nt = 0; nt < 8; ++nt) {
            bf16x8 b = *(const bf16x8*)(Wt + (nt * 16 + l15) * WSTRIDE + kofs); // B^T[n][k]
            acc[nt] = __builtin_amdgcn_mfma_f32_16x16x32_bf16(a, b, acc[nt], 0, 0, 0);
        }
    }

    // ---- Phase 3: epilogue. C/D: col = lane&15, row = quad*4 + reg ----
    #pragma unroll
    for (int nt = 0; nt < 8; ++nt) {
        const int col = nt * 16 + l15;
        const float bcol = bias[col];
        #pragma unroll
        for (int r = 0; r < 4; ++r) {
            const int row = rowbase + quad * 4 + r;
            if (row < N) out[(long long)row * 128 + col] = acc[nt][r] + bcol;
        }
    }
}

extern "C" void kernel_launch(void* const* d_in, const int* in_sizes, int n_in,
                              void* d_out, int out_size, void* d_ws, size_t ws_size,
                              hipStream_t stream) {
    const float* x    = (const float*)d_in[0];
    const int*   ei   = (const int*)d_in[1];     // int32 on device
    const float* W    = (const float*)d_in[2];
    const float* bias = (const float*)d_in[3];
    float*       out  = (float*)d_out;

    const int N = in_sizes[0] / 128;
    const int E = in_sizes[1] / 2;

    const int grid = (N + 63) / 64;   // 64 rows/block, 16 per wave
    gcn_fused<<<grid, 256, 0, stream>>>(x, ei, ei + E, W, bias, out, N, E);
}

// Round 4
// 139.989 us; speedup vs baseline: 2.9727x; 1.2844x over previous
//
#include <hip/hip_runtime.h>
#include <stdint.h>

// GCN: out[u] = (sum_{(u,v) in E} x[v]) @ W + bias, E sorted by u.
// R3 was latency-bound (VALUBusy 9%, HBM 18%): index-load -> gather chain
// ~700cyc/4 edges. R4: lane-parallel index prefetch (1 coalesced load/row,
// distributed via shfl) + float4 gathers with wave halves covering 2 edges
// per instruction, unroll-4 => 8 edges in flight, chain ~= 1 latency/row.

typedef __attribute__((ext_vector_type(8))) short bf16x8;   // 8 bf16 = 4 VGPRs
typedef __attribute__((ext_vector_type(4))) float f32x4;    // MFMA C/D

#define WSTRIDE 136   // padded k-stride (bf16 elems), multiple of 8 for 16B reads

__device__ __forceinline__ unsigned short f2bf(float f) {
    union { float f; uint32_t u; } c; c.f = f;
    uint32_t u = c.u;
    uint32_t r = (u + 0x7FFFu + ((u >> 16) & 1u)) >> 16;  // RNE
    return (unsigned short)r;
}

__global__ __launch_bounds__(256)
void gcn_fused(const float* __restrict__ x,
               const int* __restrict__ eu,   // dst row ids, sorted, int32
               const int* __restrict__ ev,   // src row ids, int32
               const float* __restrict__ W,  // [128][128] f32, k-major
               const float* __restrict__ bias,
               float* __restrict__ out,      // [N][128] f32
               int N, int E)
{
    __shared__ __align__(16) unsigned short Wt[128 * WSTRIDE];   // W^T bf16: Wt[n][k]
    __shared__ __align__(16) unsigned short At[4][16 * WSTRIDE]; // per-wave agg [m][k]

    const int t    = threadIdx.x;
    const int wid  = t >> 6;
    const int lane = t & 63;
    const int quad = lane >> 4;
    const int l15  = lane & 15;
    const int half = lane >> 5;   // 0: even edges, 1: odd edges
    const int l31  = lane & 31;   // feature quad within row (float4)

    // ---- Phase 0: W (k-major f32) -> Wt (n-major bf16), cooperative ----
    {
        const float4* W4 = (const float4*)W;
        #pragma unroll
        for (int i = 0; i < 16; ++i) {
            int flat = i * 1024 + t * 4;
            int k = flat >> 7;
            int n = flat & 127;
            float4 w = W4[flat >> 2];
            Wt[(n + 0) * WSTRIDE + k] = f2bf(w.x);
            Wt[(n + 1) * WSTRIDE + k] = f2bf(w.y);
            Wt[(n + 2) * WSTRIDE + k] = f2bf(w.z);
            Wt[(n + 3) * WSTRIDE + k] = f2bf(w.w);
        }
    }
    __syncthreads();

    // ---- Phase 1a: 17 parallel binary searches for row boundaries ----
    const int rowbase = blockIdx.x * 64 + wid * 16;
    int tgt = rowbase + (lane < 16 ? lane : 16);
    int lo = 0, hi = E;
    while (lo < hi) {
        int mid = (lo + hi) >> 1;
        if (eu[mid] < tgt) lo = mid + 1; else hi = mid;
    }

    // ---- Phase 1b: per-row gather. 2 edges per wave instruction (float4
    // halves), indices prefetched lane-parallel and distributed via shfl. ----
    unsigned short* Am = &At[wid][0];
    const float4* x4 = (const float4*)x;
    for (int m = 0; m < 16; ++m) {
        const int s   = __shfl(lo, m);
        const int cnt = __shfl(lo, m + 1) - s;
        const int* evs = ev + s;
        float4 accA = {0.f, 0.f, 0.f, 0.f};
        float4 accB = {0.f, 0.f, 0.f, 0.f};
        for (int base = 0; base < cnt; base += 64) {
            const int c = min(cnt - base, 64);
            int vIdx = (lane < c) ? evs[base + lane] : 0;  // 1 coalesced load
            int j = 0;
            for (; j + 8 <= c; j += 8) {
                int v0 = __shfl(vIdx, j + 0 + half);
                int v1 = __shfl(vIdx, j + 2 + half);
                int v2 = __shfl(vIdx, j + 4 + half);
                int v3 = __shfl(vIdx, j + 6 + half);
                float4 t0 = x4[((long long)v0 << 5) + l31];
                float4 t1 = x4[((long long)v1 << 5) + l31];
                float4 t2 = x4[((long long)v2 << 5) + l31];
                float4 t3 = x4[((long long)v3 << 5) + l31];
                accA.x += t0.x; accA.y += t0.y; accA.z += t0.z; accA.w += t0.w;
                accB.x += t1.x; accB.y += t1.y; accB.z += t1.z; accB.w += t1.w;
                accA.x += t2.x; accA.y += t2.y; accA.z += t2.z; accA.w += t2.w;
                accB.x += t3.x; accB.y += t3.y; accB.z += t3.z; accB.w += t3.w;
            }
            for (; j + 2 <= c; j += 2) {
                int v = __shfl(vIdx, j + half);
                float4 tv = x4[((long long)v << 5) + l31];
                accA.x += tv.x; accA.y += tv.y; accA.z += tv.z; accA.w += tv.w;
            }
            if (j < c) {   // odd trailing edge: low half only
                int v = __shfl(vIdx, j);
                if (half == 0) {
                    float4 tv = x4[((long long)v << 5) + l31];
                    accA.x += tv.x; accA.y += tv.y; accA.z += tv.z; accA.w += tv.w;
                }
            }
        }
        // combine the two accumulator sets, then the two wave halves
        accA.x += accB.x; accA.y += accB.y; accA.z += accB.z; accA.w += accB.w;
        accA.x += __shfl_xor(accA.x, 32);
        accA.y += __shfl_xor(accA.y, 32);
        accA.z += __shfl_xor(accA.z, 32);
        accA.w += __shfl_xor(accA.w, 32);
        if (half == 0) {   // lane l31 owns features 4*l31 .. 4*l31+3
            ushort4 pk;
            pk.x = f2bf(accA.x); pk.y = f2bf(accA.y);
            pk.z = f2bf(accA.z); pk.w = f2bf(accA.w);
            *(ushort4*)(Am + m * WSTRIDE + 4 * l31) = pk;   // 8B store, 8B-aligned
        }
    }
    __syncthreads();   // once per block; At ordering for MFMA reads

    // ---- Phase 2: [16 x 128] = A @ W via mfma_f32_16x16x32_bf16 ----
    const unsigned short* Amr = &At[wid][0];
    f32x4 acc[8];
    #pragma unroll
    for (int nt = 0; nt < 8; ++nt) { acc[nt].x = 0.f; acc[nt].y = 0.f; acc[nt].z = 0.f; acc[nt].w = 0.f; }

    #pragma unroll
    for (int ks = 0; ks < 4; ++ks) {
        const int kofs = ks * 32 + quad * 8;
        bf16x8 a = *(const bf16x8*)(Amr + l15 * WSTRIDE + kofs);  // A[m=l15][k..k+7]
        #pragma unroll
        for (int nt = 0; nt < 8; ++nt) {
            bf16x8 b = *(const bf16x8*)(Wt + (nt * 16 + l15) * WSTRIDE + kofs); // B^T[n][k]
            acc[nt] = __builtin_amdgcn_mfma_f32_16x16x32_bf16(a, b, acc[nt], 0, 0, 0);
        }
    }

    // ---- Phase 3: epilogue. C/D: col = lane&15, row = quad*4 + reg ----
    #pragma unroll
    for (int nt = 0; nt < 8; ++nt) {
        const int col = nt * 16 + l15;
        const float bcol = bias[col];
        #pragma unroll
        for (int r = 0; r < 4; ++r) {
            const int row = rowbase + quad * 4 + r;
            if (row < N) out[(long long)row * 128 + col] = acc[nt][r] + bcol;
        }
    }
}

extern "C" void kernel_launch(void* const* d_in, const int* in_sizes, int n_in,
                              void* d_out, int out_size, void* d_ws, size_t ws_size,
                              hipStream_t stream) {
    const float* x    = (const float*)d_in[0];
    const int*   ei   = (const int*)d_in[1];     // int32 on device
    const float* W    = (const float*)d_in[2];
    const float* bias = (const float*)d_in[3];
    float*       out  = (float*)d_out;

    const int N = in_sizes[0] / 128;
    const int E = in_sizes[1] / 2;

    const int grid = (N + 63) / 64;   // 64 rows/block, 16 per wave
    gcn_fused<<<grid, 256, 0, stream>>>(x, ei, ei + E, W, bias, out, N, E);
}

// Round 5
// 136.459 us; speedup vs baseline: 3.0496x; 1.0259x over previous
//
#include <hip/hip_runtime.h>
#include <stdint.h>

// GCN: out[u] = (sum_{(u,v) in E} x[v]) @ W + bias, E sorted by u.
// R4 was still latency-bound (VALUBusy 11%, HBM 28%): serial tail iterations
// (~4-5 round trips/row), per-wave 20-deep binary search, LDS-capped occupancy.
// R5: (a) setup kernel precomputes CSR row_ptr + bf16 W^T into d_ws;
//     (b) main kernel: fixed 8-slot predicated gather (one vmcnt wait/row),
//         next-row index prefetch, B-frags straight from global (L2-hot),
//         LDS = A-tiles only (17KB) -> all blocks co-resident, zero barriers.

typedef __attribute__((ext_vector_type(8))) short bf16x8;   // 8 bf16 = 4 VGPRs
typedef __attribute__((ext_vector_type(4))) float f32x4;    // MFMA C/D

#define WSTRIDE 136   // A-tile k-stride (bf16 elems), multiple of 8 for 16B reads

__device__ __forceinline__ unsigned short f2bf(float f) {
    union { float f; uint32_t u; } c; c.f = f;
    uint32_t u = c.u;
    uint32_t r = (u + 0x7FFFu + ((u >> 16) & 1u)) >> 16;  // RNE
    return (unsigned short)r;
}

__global__ __launch_bounds__(256)
void gcn_setup(const int* __restrict__ eu, const float* __restrict__ W,
               int* __restrict__ row_ptr, unsigned short* __restrict__ Wg,
               int N, int E)
{
    const int g = blockIdx.x * 256 + threadIdx.x;
    if (g <= N) {                       // row_ptr[g] = lower_bound(eu, g)
        int lo = 0, hi = E;
        while (lo < hi) {
            int mid = (lo + hi) >> 1;
            if (eu[mid] < g) lo = mid + 1; else hi = mid;
        }
        row_ptr[g] = lo;
    }
    const int w = g - (N + 1);          // W^T bf16: Wg[n*128+k] = bf16(W[k][n])
    if (w >= 0 && w < 16384) {
        int n = w >> 7, k = w & 127;
        Wg[w] = f2bf(W[k * 128 + n]);
    }
}

__global__ __launch_bounds__(256)
void gcn_main(const float* __restrict__ x,
              const int* __restrict__ ev,        // src ids, int32
              const int* __restrict__ row_ptr,   // [N+1]
              const unsigned short* __restrict__ Wg,  // bf16 W^T [128][128]
              const float* __restrict__ bias,
              float* __restrict__ out,           // [N][128] f32
              int N, int E)
{
    __shared__ __align__(16) unsigned short At[4][16 * WSTRIDE]; // per-wave agg [m][k]

    const int t    = threadIdx.x;
    const int wid  = t >> 6;
    const int lane = t & 63;
    const int quad = lane >> 4;
    const int l15  = lane & 15;
    const int half = lane >> 5;   // 0/1: which edge of the pair
    const int l31  = lane & 31;   // float4 slot within a 128-f row

    const int rowbase = blockIdx.x * 64 + wid * 16;

    // ---- Row boundaries: one coalesced load (CSR precomputed) ----
    const int bq  = rowbase + (lane < 17 ? lane : 16);
    const int bnd = row_ptr[min(bq, N)];

    unsigned short* Am = &At[wid][0];
    const float4* x4 = (const float4*)x;

    // prefetch row 0's first 64 edge indices
    int vIdx = ev[min(__shfl(bnd, 0) + lane, E - 1)];

    for (int m = 0; m < 16; ++m) {
        const int s  = __shfl(bnd, m);
        const int sn = __shfl(bnd, m + 1);
        const int c  = sn - s;
        // prefetch next row's indices BEFORE this row's gather-wait
        int vNext = (m < 15) ? ev[min(sn + lane, E - 1)] : 0;

        float4 acc0 = {0.f, 0.f, 0.f, 0.f};
        float4 acc1 = {0.f, 0.f, 0.f, 0.f};
        for (int base = 0; base < c; base += 16) {
            if (base && ((base & 63) == 0))               // c > 64: ~never
                vIdx = ev[min(s + base + lane, E - 1)];
            const int boff = base & 63;
            float4 tv[8];
            float  sc[8];
            #pragma unroll
            for (int k = 0; k < 8; ++k) {                 // issue ALL loads first
                const int eidx = base + 2 * k + half;
                const int slot = (boff + 2 * k + half) & 63;
                const int v = __shfl(vIdx, slot);         // valid edge id even if inactive
                sc[k] = (eidx < c) ? 1.0f : 0.0f;
                tv[k] = x4[((long long)v << 5) + l31];
            }
            #pragma unroll
            for (int k = 0; k < 8; ++k) {                 // one wait, then fma
                float4& a = (k & 1) ? acc1 : acc0;
                a.x = fmaf(tv[k].x, sc[k], a.x);
                a.y = fmaf(tv[k].y, sc[k], a.y);
                a.z = fmaf(tv[k].z, sc[k], a.z);
                a.w = fmaf(tv[k].w, sc[k], a.w);
            }
        }
        vIdx = vNext;

        // combine accumulator pair, then the two wave halves
        acc0.x += acc1.x; acc0.y += acc1.y; acc0.z += acc1.z; acc0.w += acc1.w;
        acc0.x += __shfl_xor(acc0.x, 32);
        acc0.y += __shfl_xor(acc0.y, 32);
        acc0.z += __shfl_xor(acc0.z, 32);
        acc0.w += __shfl_xor(acc0.w, 32);
        if (half == 0) {   // lane l31 owns features 4*l31 .. 4*l31+3
            ushort4 pk;
            pk.x = f2bf(acc0.x); pk.y = f2bf(acc0.y);
            pk.z = f2bf(acc0.z); pk.w = f2bf(acc0.w);
            *(ushort4*)(Am + m * WSTRIDE + 4 * l31) = pk;   // 8B aligned
        }
    }
    // No barrier: At tile is wave-private; same-wave LDS ops are ordered.

    // ---- MFMA: [16 x 128] = A @ W, B-frags straight from global (L2-hot) ----
    f32x4 acc[8];
    #pragma unroll
    for (int nt = 0; nt < 8; ++nt) { acc[nt].x = 0.f; acc[nt].y = 0.f; acc[nt].z = 0.f; acc[nt].w = 0.f; }

    #pragma unroll
    for (int ks = 0; ks < 4; ++ks) {
        const int kofs = ks * 32 + quad * 8;
        bf16x8 a = *(const bf16x8*)(Am + l15 * WSTRIDE + kofs);       // A[m=l15][k..k+7]
        #pragma unroll
        for (int nt = 0; nt < 8; ++nt) {
            bf16x8 b = *(const bf16x8*)(Wg + (nt * 16 + l15) * 128 + kofs); // B^T[n][k]
            acc[nt] = __builtin_amdgcn_mfma_f32_16x16x32_bf16(a, b, acc[nt], 0, 0, 0);
        }
    }

    // ---- Epilogue. C/D: col = lane&15, row = quad*4 + reg ----
    #pragma unroll
    for (int nt = 0; nt < 8; ++nt) {
        const int col = nt * 16 + l15;
        const float bcol = bias[col];
        #pragma unroll
        for (int r = 0; r < 4; ++r) {
            const int row = rowbase + quad * 4 + r;
            if (row < N) out[(long long)row * 128 + col] = acc[nt][r] + bcol;
        }
    }
}

extern "C" void kernel_launch(void* const* d_in, const int* in_sizes, int n_in,
                              void* d_out, int out_size, void* d_ws, size_t ws_size,
                              hipStream_t stream) {
    const float* x    = (const float*)d_in[0];
    const int*   ei   = (const int*)d_in[1];     // int32 on device
    const float* W    = (const float*)d_in[2];
    const float* bias = (const float*)d_in[3];
    float*       out  = (float*)d_out;

    const int N = in_sizes[0] / 128;
    const int E = in_sizes[1] / 2;

    int*            row_ptr = (int*)d_ws;                                  // (N+1)*4 B
    unsigned short* Wg      = (unsigned short*)((char*)d_ws + (((size_t)(N + 1) * 4 + 255) & ~(size_t)255)); // 32 KB

    const int setup_threads = (N + 1) + 16384;
    gcn_setup<<<(setup_threads + 255) / 256, 256, 0, stream>>>(ei, W, row_ptr, Wg, N, E);

    const int grid = (N + 63) / 64;   // 64 rows/block, 16 per wave
    gcn_main<<<grid, 256, 0, stream>>>(x, ei + E, row_ptr, Wg, bias, out, N, E);
}